// Round 1
// baseline (79.940 us; speedup 1.0000x reference)
//
#include <hip/hip_runtime.h>
#include <hip/hip_bf16.h>

typedef __attribute__((ext_vector_type(8))) short short8;
typedef __attribute__((ext_vector_type(4))) float floatx4;

#define L2EPS 1e-12f

__device__ __forceinline__ unsigned short f2bf(float f) {
  union { float f; unsigned u; } c; c.f = f;
  unsigned u = c.u;
  unsigned r = (u + 0x7fffu + ((u >> 16) & 1u)) >> 16;  // RNE
  return (unsigned short)r;
}

__device__ __forceinline__ void gload_lds16(const void* g, void* l) {
  __builtin_amdgcn_global_load_lds(
      (const __attribute__((address_space(1))) unsigned int*)g,
      (__attribute__((address_space(3))) unsigned int*)l,
      16, 0, 0);
}

// ---------------------------------------------------------------------------
// Kernel 1: normalize rows of x (B x 512), emit bf16. One wave per row.
// ---------------------------------------------------------------------------
__global__ __launch_bounds__(256) void xnorm_kernel(const float* __restrict__ x,
                                                    unsigned short* __restrict__ xb) {
  const int lane = threadIdx.x & 63;
  const int wave = threadIdx.x >> 6;
  const int row  = blockIdx.x * 4 + wave;
  const float4* xr = (const float4*)(x + (size_t)row * 512);
  const float4 v0 = xr[lane * 2];
  const float4 v1 = xr[lane * 2 + 1];
  float s = v0.x*v0.x + v0.y*v0.y + v0.z*v0.z + v0.w*v0.w
          + v1.x*v1.x + v1.y*v1.y + v1.z*v1.z + v1.w*v1.w;
#pragma unroll
  for (int off = 32; off > 0; off >>= 1) s += __shfl_xor(s, off);
  const float r = rsqrtf(fmaxf(s, L2EPS));
  short8 o;
  o[0] = (short)f2bf(v0.x * r); o[1] = (short)f2bf(v0.y * r);
  o[2] = (short)f2bf(v0.z * r); o[3] = (short)f2bf(v0.w * r);
  o[4] = (short)f2bf(v1.x * r); o[5] = (short)f2bf(v1.y * r);
  o[6] = (short)f2bf(v1.z * r); o[7] = (short)f2bf(v1.w * r);
  *(short8*)(xb + (size_t)row * 512 + lane * 8) = o;
}

// ---------------------------------------------------------------------------
// Kernel 2: per-row inverse L2 norm of W (D rows of length N). One block/row.
// ---------------------------------------------------------------------------
__global__ __launch_bounds__(256) void wnorm_kernel(const float* __restrict__ W,
                                                    float* __restrict__ rnw, int N) {
  const int d = blockIdx.x;
  const float2* row2 = (const float2*)(W + (size_t)d * N);
  const int n2 = N >> 1;
  float s = 0.f;
  for (int i = threadIdx.x; i < n2; i += 256) {
    const float2 v = row2[i];
    s += v.x * v.x + v.y * v.y;
  }
  if (threadIdx.x == 0 && (N & 1)) {
    const float v = W[(size_t)d * N + (N - 1)];
    s += v * v;
  }
#pragma unroll
  for (int off = 32; off > 0; off >>= 1) s += __shfl_xor(s, off);
  __shared__ float red[4];
  if ((threadIdx.x & 63) == 0) red[threadIdx.x >> 6] = s;
  __syncthreads();
  if (threadIdx.x == 0) {
    const float t = red[0] + red[1] + red[2] + red[3];
    rnw[d] = rsqrtf(fmaxf(t, L2EPS));
  }
}

// ---------------------------------------------------------------------------
// Kernel 3: BT[n][d] = bf16(W[d][n] * rnw[d]), n in [0,Npad) zero-padded.
// 32x32 LDS transpose tiles, 256 threads (32x8).
// ---------------------------------------------------------------------------
__global__ __launch_bounds__(256) void wtrans_kernel(const float* __restrict__ W,
                                                     const float* __restrict__ rnw,
                                                     unsigned short* __restrict__ BT,
                                                     int N, int K) {
  __shared__ unsigned short tile[32][33];
  const int n0 = blockIdx.x * 32;
  const int d0 = blockIdx.y * 32;
  const int tx = threadIdx.x & 31;
  const int ty = threadIdx.x >> 5;  // 0..7
#pragma unroll
  for (int i = 0; i < 4; ++i) {
    const int dl = ty + i * 8;
    const int d = d0 + dl;
    const int n = n0 + tx;
    float v = 0.f;
    if (n < N) v = W[(size_t)d * N + n] * rnw[d];
    tile[tx][dl] = f2bf(v);
  }
  __syncthreads();
#pragma unroll
  for (int i = 0; i < 4; ++i) {
    const int nl = ty + i * 8;
    BT[(size_t)(n0 + nl) * K + d0 + tx] = tile[nl][tx];
  }
}

// ---------------------------------------------------------------------------
// Kernel 4: bf16 MFMA GEMM. C[M,N] = A[M,K] * BT[Npad,K]^T.
// 128x128 tile, BK=64, 4 waves (2x2), 16x16x32 MFMA, 4x4 frags/wave.
// global_load_lds width-16 staging (m97 structure).
// ---------------------------------------------------------------------------
#define BM 128
#define BN 128
#define BK 64

__global__ __launch_bounds__(256) void gemm_kernel(
    const unsigned short* __restrict__ A,   // (M,K) bf16
    const unsigned short* __restrict__ BT,  // (Npad,K) bf16
    float* __restrict__ C,                  // (M,N) f32
    int M, int N, int Npad, int K) {
  __shared__ unsigned short As[BM * BK];
  __shared__ unsigned short Bs[BN * BK];

  const int tid  = threadIdx.x;
  const int lane = tid & 63;
  const int wave = tid >> 6;
  const int wr = wave >> 1;  // 0..1
  const int wc = wave & 1;   // 0..1

  const int row0 = blockIdx.y * BM;
  const int col0 = blockIdx.x * BN;

  floatx4 acc[4][4];
#pragma unroll
  for (int m = 0; m < 4; ++m)
#pragma unroll
    for (int n = 0; n < 4; ++n)
      acc[m][n] = (floatx4){0.f, 0.f, 0.f, 0.f};

  // staging decomposition: thread handles 16B chunks
  const int srow = tid >> 3;        // 0..31
  const int scol = (tid & 7) * 8;   // 0,8,..,56

  const unsigned short* Ag = A  + (size_t)row0 * K + scol;
  const unsigned short* Bg = BT + (size_t)col0 * K + scol;

  for (int kt = 0; kt < K; kt += BK) {
#pragma unroll
    for (int it = 0; it < 4; ++it) {
      const int r = it * 32 + srow;
      gload_lds16(Ag + (size_t)r * K + kt, &As[r * BK + scol]);
      gload_lds16(Bg + (size_t)r * K + kt, &Bs[r * BK + scol]);
    }
    __syncthreads();
#pragma unroll
    for (int ks = 0; ks < 2; ++ks) {
      const int kk = ks * 32 + (lane >> 4) * 8;
      short8 af[4], bfr[4];
#pragma unroll
      for (int m = 0; m < 4; ++m)
        af[m] = *(const short8*)&As[(wr * 64 + m * 16 + (lane & 15)) * BK + kk];
#pragma unroll
      for (int n = 0; n < 4; ++n)
        bfr[n] = *(const short8*)&Bs[(wc * 64 + n * 16 + (lane & 15)) * BK + kk];
#pragma unroll
      for (int m = 0; m < 4; ++m)
#pragma unroll
        for (int n = 0; n < 4; ++n)
          acc[m][n] = __builtin_amdgcn_mfma_f32_16x16x32_bf16(af[m], bfr[n], acc[m][n], 0, 0, 0);
    }
    __syncthreads();
  }

  // epilogue: C/D layout col=lane&15, row=(lane>>4)*4+r  [m89/m91 verified]
  const int rbase = row0 + wr * 64 + (lane >> 4) * 4;
  const int cbase = col0 + wc * 64 + (lane & 15);
#pragma unroll
  for (int n = 0; n < 4; ++n) {
    const int col = cbase + n * 16;
    if (col < N) {
#pragma unroll
      for (int m = 0; m < 4; ++m) {
        const int row = rbase + m * 16;
#pragma unroll
        for (int r = 0; r < 4; ++r)
          C[(size_t)(row + r) * N + col] = acc[m][n][r];
      }
    }
  }
}

// ---------------------------------------------------------------------------
extern "C" void kernel_launch(void* const* d_in, const int* in_sizes, int n_in,
                              void* d_out, int out_size, void* d_ws, size_t ws_size,
                              hipStream_t stream) {
  const float* x = (const float*)d_in[0];
  const float* W = (const float*)d_in[1];
  float* out = (float*)d_out;

  const int D = 512;
  const int B = in_sizes[0] / D;        // 4096
  const int N = in_sizes[1] / D;        // 5994
  const int Npad = ((N + 127) / 128) * 128;  // 6016

  char* ws = (char*)d_ws;
  unsigned short* xb  = (unsigned short*)ws;                          // B*D*2
  unsigned short* BTb = (unsigned short*)(ws + (size_t)B * D * 2);    // Npad*D*2
  float* rnw = (float*)(ws + (size_t)B * D * 2 + (size_t)Npad * D * 2);

  xnorm_kernel<<<B / 4, 256, 0, stream>>>(x, xb);
  wnorm_kernel<<<D, 256, 0, stream>>>(W, rnw, N);
  wtrans_kernel<<<dim3(Npad / 32, D / 32), 256, 0, stream>>>(W, rnw, BTb, N, D);
  gemm_kernel<<<dim3(Npad / BN, B / BM), 256, 0, stream>>>(xb, BTb, out, B, N, Npad, D);
}